// Round 1
// baseline (361.548 us; speedup 1.0000x reference)
//
#include <hip/hip_runtime.h>
#include <hip/hip_bf16.h>
#include <math.h>

typedef __bf16 bf16_t;
typedef __bf16 bf16x8 __attribute__((ext_vector_type(8)));
typedef float f32x4 __attribute__((ext_vector_type(4)));

#define BB 8
#define LL 512
#define CIN 21
#define DM 512
#define DI 1024
#define DS 16
#define RK 32
#define PL 96
#define NROW (BB*LL)   // 4096

// workspace layout (bytes). emb/WinT are dead after k_gemm; BC/yfin reuse that region.
#define EMB_OFF   0u                 // bf16 4096*512   (4 MB)   [dead after gemm]
#define BC_OFF    0u                 // f32  4096*32    (512 KB) [written after gemm]
#define YFIN_OFF  (1u<<20)           // f32  768*1024   (3 MB)   [written after gemm]
#define WINT_OFF  (4u<<20)           // bf16 2048*512   (2 MB)   [dead after gemm]
#define WCOMB_OFF (6u<<20)           // f32  1024*21
#define STATS_OFF (7u<<20)           // f32  mean[168], std[168]
#define XZ_OFF    (8u<<20)           // bf16 4096*2048  (16 MB)
#define XS_OFF    (24u<<20)          // f32  4096*1024  (16 MB)
#define DT_OFF    (40u<<20)          // f32  4096*1024  (16 MB)

static __device__ __forceinline__ float softplusf(float x) {
    return (x > 20.f) ? x : log1pf(__expf(x));
}
static __device__ __forceinline__ float siluf(float x) {
    return x / (1.f + __expf(-x));
}

// ---------------- per-(b,c) mean / std over L ----------------
__global__ void k_stats(const float* __restrict__ x, float* __restrict__ meanW,
                        float* __restrict__ stdW) {
    int bc = blockIdx.x; int b = bc / CIN, c = bc % CIN;
    const float* p = x + (size_t)b * LL * CIN + c;
    float s = 0.f, ss = 0.f;
    for (int t = threadIdx.x; t < LL; t += 256) {
        float v = p[(size_t)t * CIN];
        s += v; ss += v * v;
    }
    __shared__ float r1[256], r2[256];
    r1[threadIdx.x] = s; r2[threadIdx.x] = ss;
    __syncthreads();
    for (int off = 128; off > 0; off >>= 1) {
        if (threadIdx.x < off) {
            r1[threadIdx.x] += r1[threadIdx.x + off];
            r2[threadIdx.x] += r2[threadIdx.x + off];
        }
        __syncthreads();
    }
    if (threadIdx.x == 0) {
        float m = r1[0] / LL;
        float var = r2[0] / LL - m * m;
        meanW[bc] = m;
        stdW[bc]  = sqrtf(var + 1e-5f);
    }
}

// ---------------- embedding: xn @ W_emb + b_emb -> bf16 ----------------
__global__ void k_emb(const float* __restrict__ x, const float* __restrict__ W,
                      const float* __restrict__ bias, const float* __restrict__ meanW,
                      const float* __restrict__ stdW, bf16_t* __restrict__ emb) {
    int row0 = blockIdx.x * 4;           // 4 rows per block; 512%4==0 so same batch
    int b = row0 >> 9;
    __shared__ float xn[4][CIN];
    int tid = threadIdx.x;
    if (tid < 4 * CIN) {
        int r = tid / CIN, c = tid % CIN;
        xn[r][c] = (x[(size_t)(row0 + r) * CIN + c] - meanW[b * CIN + c]) / stdW[b * CIN + c];
    }
    __syncthreads();
    int j0 = tid, j1 = tid + 256;
    float acc[4][2];
    float b0 = bias[j0], b1 = bias[j1];
    for (int r = 0; r < 4; ++r) { acc[r][0] = b0; acc[r][1] = b1; }
    for (int c = 0; c < CIN; ++c) {
        float w0 = W[c * DM + j0], w1 = W[c * DM + j1];
        for (int r = 0; r < 4; ++r) {
            acc[r][0] += xn[r][c] * w0;
            acc[r][1] += xn[r][c] * w1;
        }
    }
    for (int r = 0; r < 4; ++r) {
        emb[(size_t)(row0 + r) * DM + j0] = (bf16_t)acc[r][0];
        emb[(size_t)(row0 + r) * DM + j1] = (bf16_t)acc[r][1];
    }
}

// ---------------- W_in (512,2048) f32 -> W_in^T (2048,512) bf16 ----------------
__global__ void k_wint(const float* __restrict__ Win, bf16_t* __restrict__ WinT) {
    __shared__ float tile[32][33];
    int k0 = blockIdx.x * 32, n0 = blockIdx.y * 32;
    int x = threadIdx.x, y = threadIdx.y;
    for (int i = 0; i < 4; ++i)
        tile[y + 8 * i][x] = Win[(size_t)(k0 + y + 8 * i) * (2 * DI) + n0 + x];
    __syncthreads();
    for (int i = 0; i < 4; ++i)
        WinT[(size_t)(n0 + y + 8 * i) * DM + k0 + x] = (bf16_t)tile[x][y + 8 * i];
}

// ---------------- Wcomb = W_op @ W_head  (1024x21) ----------------
__global__ void k_wcomb(const float* __restrict__ Wop, const float* __restrict__ Wh,
                        float* __restrict__ Wc) {
    int i = blockIdx.x;
    __shared__ float row[DM];
    __shared__ float part[8][32];
    int tid = threadIdx.x;
    row[tid] = Wop[(size_t)i * DM + tid];
    row[tid + 256] = Wop[(size_t)i * DM + tid + 256];
    __syncthreads();
    int c = tid & 31, seg = tid >> 5;
    float p = 0.f;
    if (c < CIN) {
        for (int kk = 0; kk < 64; ++kk) {
            int k = seg * 64 + kk;
            p += row[k] * Wh[k * CIN + c];
        }
    }
    part[seg][c] = p;
    __syncthreads();
    if (tid < CIN) {
        float s = 0.f;
        for (int g = 0; g < 8; ++g) s += part[g][tid];
        Wc[i * CIN + tid] = s;
    }
}

// ---------------- big GEMM: xz = emb(4096x512) @ W_in  via bf16 MFMA ----------------
// A row-major (M,K) bf16, Bt row-major (N,K) bf16, C (M,2048) bf16
__launch_bounds__(256, 2)
__global__ void k_gemm(const bf16_t* __restrict__ A, const bf16_t* __restrict__ Bt,
                       bf16_t* __restrict__ C) {
    __shared__ bf16_t As[128 * 40];   // 32 data + 8 pad per row (80B, 16B-aligned)
    __shared__ bf16_t Bs[128 * 40];
    int m0 = blockIdx.x * 128, n0 = blockIdx.y * 128;
    int tid = threadIdx.x;
    int lane = tid & 63, wv = tid >> 6;
    int wr = wv >> 1, wc = wv & 1;
    int lr = lane & 15, lk = lane >> 4;
    f32x4 acc[4][4];
    for (int i = 0; i < 4; ++i)
        for (int j = 0; j < 4; ++j)
            acc[i][j] = (f32x4){0.f, 0.f, 0.f, 0.f};
    int srow = tid >> 2, scb = tid & 3;
    for (int kt = 0; kt < 16; ++kt) {
        int k0 = kt * 32;
        uint4 va0 = *(const uint4*)(A + (size_t)(m0 + srow) * DM + k0 + scb * 8);
        uint4 va1 = *(const uint4*)(A + (size_t)(m0 + srow + 64) * DM + k0 + scb * 8);
        uint4 vb0 = *(const uint4*)(Bt + (size_t)(n0 + srow) * DM + k0 + scb * 8);
        uint4 vb1 = *(const uint4*)(Bt + (size_t)(n0 + srow + 64) * DM + k0 + scb * 8);
        __syncthreads();
        *(uint4*)&As[srow * 40 + scb * 8] = va0;
        *(uint4*)&As[(srow + 64) * 40 + scb * 8] = va1;
        *(uint4*)&Bs[srow * 40 + scb * 8] = vb0;
        *(uint4*)&Bs[(srow + 64) * 40 + scb * 8] = vb1;
        __syncthreads();
        bf16x8 af[4], bfr[4];
        for (int i = 0; i < 4; ++i)
            af[i] = *(const bf16x8*)&As[(wr * 64 + i * 16 + lr) * 40 + lk * 8];
        for (int j = 0; j < 4; ++j)
            bfr[j] = *(const bf16x8*)&Bs[(wc * 64 + j * 16 + lr) * 40 + lk * 8];
        for (int i = 0; i < 4; ++i)
            for (int j = 0; j < 4; ++j)
                acc[i][j] = __builtin_amdgcn_mfma_f32_16x16x32_bf16(af[i], bfr[j], acc[i][j], 0, 0, 0);
    }
    for (int i = 0; i < 4; ++i)
        for (int j = 0; j < 4; ++j) {
            int col = n0 + wc * 64 + j * 16 + lr;
            int rbase = m0 + wr * 64 + i * 16 + lk * 4;
            for (int e = 0; e < 4; ++e)
                C[(size_t)(rbase + e) * (2 * DI) + col] = (bf16_t)acc[i][j][e];
        }
}

// ---------------- causal depthwise conv(k=4) + silu ----------------
__global__ void k_conv(const bf16_t* __restrict__ xz, const float* __restrict__ cw,
                       const float* __restrict__ cb, float* __restrict__ xs_act) {
    int g = blockIdx.x * 256 + threadIdx.x;    // 0 .. 4096*1024-1
    int d = g & (DI - 1);
    int bt = g >> 10;
    int t = bt & (LL - 1);
    const bf16_t* p = xz + (size_t)bt * (2 * DI) + d;
    float4 w = *(const float4*)(cw + d * 4);
    float acc = cb[d];
    float x0 = (t >= 3) ? (float)p[-3 * 2048] : 0.f;
    float x1 = (t >= 2) ? (float)p[-2 * 2048] : 0.f;
    float x2 = (t >= 1) ? (float)p[-1 * 2048] : 0.f;
    float x3 = (float)p[0];
    acc += w.x * x0 + w.y * x1 + w.z * x2 + w.w * x3;
    xs_act[g] = siluf(acc);
}

// ---------------- dbc = xs@W_xp ; dt = softplus(dbc[:, :32]@W_dt + b_dt) ; B,C out ----
__global__ void k_dbcdt(const float* __restrict__ xs, const float* __restrict__ Wxp,
                        const float* __restrict__ Wdt, const float* __restrict__ bdt,
                        float* __restrict__ BC, float* __restrict__ dtO) {
    int bt0 = blockIdx.x * 4;
    __shared__ float xsL[4][DI];
    __shared__ float part[4][4][64];
    __shared__ float dbcL[4][64];
    int tid = threadIdx.x;
    for (int r = 0; r < 4; ++r)
        for (int i = tid; i < DI; i += 256)
            xsL[r][i] = xs[(size_t)(bt0 + r) * DI + i];
    __syncthreads();
    int j = tid & 63, cseg = tid >> 6;
    float p0 = 0, p1 = 0, p2 = 0, p3 = 0;
    for (int kk = 0; kk < 256; ++kk) {
        int k = cseg * 256 + kk;
        float w = Wxp[(size_t)k * 64 + j];
        p0 += xsL[0][k] * w; p1 += xsL[1][k] * w;
        p2 += xsL[2][k] * w; p3 += xsL[3][k] * w;
    }
    part[cseg][0][j] = p0; part[cseg][1][j] = p1;
    part[cseg][2][j] = p2; part[cseg][3][j] = p3;
    __syncthreads();
    {
        int jj = tid & 63, r = tid >> 6;
        float v = part[0][r][jj] + part[1][r][jj] + part[2][r][jj] + part[3][r][jj];
        dbcL[r][jj] = v;
        if (jj >= 32) BC[(size_t)(bt0 + r) * 32 + (jj - 32)] = v;
    }
    __syncthreads();
    for (int jo = tid; jo < DI; jo += 256) {
        float bb = bdt[jo];
        float a0 = bb, a1 = bb, a2 = bb, a3 = bb;
        for (int rk = 0; rk < RK; ++rk) {
            float w = Wdt[(size_t)rk * DI + jo];
            a0 += dbcL[0][rk] * w; a1 += dbcL[1][rk] * w;
            a2 += dbcL[2][rk] * w; a3 += dbcL[3][rk] * w;
        }
        dtO[(size_t)(bt0 + 0) * DI + jo] = softplusf(a0);
        dtO[(size_t)(bt0 + 1) * DI + jo] = softplusf(a1);
        dtO[(size_t)(bt0 + 2) * DI + jo] = softplusf(a2);
        dtO[(size_t)(bt0 + 3) * DI + jo] = softplusf(a3);
    }
}

// ---------------- selective scan + gate; writes only last PL steps ----------------
__global__ void k_scan(const float* __restrict__ dt, const float* __restrict__ xs,
                       const float* __restrict__ BC, const bf16_t* __restrict__ xz,
                       const float* __restrict__ Alog, const float* __restrict__ Dp,
                       float* __restrict__ yfin) {
    int blk = blockIdx.x;              // 512 blocks
    int b = blk >> 6;
    int dbase = (blk & 63) * 16;
    int tid = threadIdx.x;
    int s = tid & 15, dl = tid >> 4;
    int d = dbase + dl;
    float A = -__expf(Alog[d * DS + s]);
    float Dd = Dp[d];
    const float* dtp = dt + (size_t)b * LL * DI + d;
    const float* xsp = xs + (size_t)b * LL * DI + d;
    const float* bcp = BC + (size_t)b * LL * 32;
    const bf16_t* zp = xz + (size_t)b * LL * (2 * DI) + DI + d;
    float h = 0.f;
    for (int t = 0; t < LL; ++t) {
        float dtv = dtp[(size_t)t * DI];
        float xv  = xsp[(size_t)t * DI];
        float Bv  = bcp[t * 32 + s];
        float Cv  = bcp[t * 32 + 16 + s];
        h = h * __expf(dtv * A) + (dtv * xv) * Bv;
        float p = h * Cv;
        p += __shfl_xor(p, 1);
        p += __shfl_xor(p, 2);
        p += __shfl_xor(p, 4);
        p += __shfl_xor(p, 8);
        if (t >= LL - PL && s == 0) {
            float zv = (float)zp[(size_t)t * (2 * DI)];
            float yv = p + xv * Dd;
            yfin[(size_t)(b * PL + (t - (LL - PL))) * DI + d] = yv * siluf(zv);
        }
    }
}

// ---------------- out = (yfin @ Wcomb + b_head) * std + mean ----------------
__global__ void k_head(const float* __restrict__ yfin, const float* __restrict__ Wc,
                       const float* __restrict__ bh, const float* __restrict__ meanW,
                       const float* __restrict__ stdW, float* __restrict__ out) {
    int row = blockIdx.x;              // 768 = 8*96
    int b = row / PL;
    __shared__ float yL[DI];
    __shared__ float part[8][32];
    int tid = threadIdx.x;
    *(float4*)&yL[tid * 4] = *(const float4*)&yfin[(size_t)row * DI + tid * 4];
    __syncthreads();
    int c = tid & 31, seg = tid >> 5;
    float acc = 0.f;
    if (c < CIN) {
        for (int kk = 0; kk < 128; ++kk) {
            int k = seg * 128 + kk;
            acc += yL[k] * Wc[k * CIN + c];
        }
    }
    part[seg][c] = acc;
    __syncthreads();
    if (tid < CIN) {
        float sum = bh[tid];
        for (int g = 0; g < 8; ++g) sum += part[g][tid];
        out[(size_t)row * CIN + tid] = sum * stdW[b * CIN + tid] + meanW[b * CIN + tid];
    }
}

extern "C" void kernel_launch(void* const* d_in, const int* in_sizes, int n_in,
                              void* d_out, int out_size, void* d_ws, size_t ws_size,
                              hipStream_t stream) {
    const float* x_enc  = (const float*)d_in[0];
    const float* W_emb  = (const float*)d_in[4];
    const float* b_emb  = (const float*)d_in[5];
    const float* W_in   = (const float*)d_in[6];
    const float* conv_w = (const float*)d_in[7];
    const float* conv_b = (const float*)d_in[8];
    const float* W_xp   = (const float*)d_in[9];
    const float* W_dt   = (const float*)d_in[10];
    const float* b_dt   = (const float*)d_in[11];
    const float* A_log  = (const float*)d_in[12];
    const float* Dp     = (const float*)d_in[13];
    const float* W_op   = (const float*)d_in[14];
    const float* W_head = (const float*)d_in[15];
    const float* b_head = (const float*)d_in[16];

    char* ws = (char*)d_ws;
    bf16_t* emb   = (bf16_t*)(ws + EMB_OFF);
    bf16_t* WinT  = (bf16_t*)(ws + WINT_OFF);
    float*  Wcomb = (float*)(ws + WCOMB_OFF);
    float*  meanW = (float*)(ws + STATS_OFF);
    float*  stdW  = meanW + 256;
    bf16_t* xz    = (bf16_t*)(ws + XZ_OFF);
    float*  xsact = (float*)(ws + XS_OFF);
    float*  dtb   = (float*)(ws + DT_OFF);
    float*  BCb   = (float*)(ws + BC_OFF);
    float*  yfin  = (float*)(ws + YFIN_OFF);
    float*  outp  = (float*)d_out;

    k_stats<<<BB * CIN, 256, 0, stream>>>(x_enc, meanW, stdW);
    k_emb<<<NROW / 4, 256, 0, stream>>>(x_enc, W_emb, b_emb, meanW, stdW, emb);
    k_wint<<<dim3(DM / 32, (2 * DI) / 32), dim3(32, 8), 0, stream>>>(W_in, WinT);
    k_wcomb<<<DI, 256, 0, stream>>>(W_op, W_head, Wcomb);
    k_gemm<<<dim3(NROW / 128, (2 * DI) / 128), 256, 0, stream>>>(emb, WinT, xz);
    k_conv<<<(NROW * DI) / 256, 256, 0, stream>>>(xz, conv_w, conv_b, xsact);
    k_dbcdt<<<NROW / 4, 256, 0, stream>>>(xsact, W_xp, W_dt, b_dt, BCb, dtb);
    k_scan<<<BB * (DI / 16), 256, 0, stream>>>(dtb, xsact, BCb, xz, A_log, Dp, yfin);
    k_head<<<BB * PL, 256, 0, stream>>>(yfin, Wcomb, b_head, meanW, stdW, outp);
}

// Round 2
// 175.759 us; speedup vs baseline: 2.0571x; 2.0571x over previous
//
#include <hip/hip_runtime.h>
#include <hip/hip_bf16.h>
#include <math.h>

typedef __bf16 bf16_t;
typedef __bf16 bf16x8 __attribute__((ext_vector_type(8)));
typedef float f32x4 __attribute__((ext_vector_type(4)));

#define BB 8
#define LL 512
#define CIN 21
#define DM 512
#define DI 1024
#define DS 16
#define RK 32
#define PL 96
#define NROW (BB*LL)   // 4096
#define NCH 16         // scan chunks
#define TC 32          // steps per chunk (LL/NCH)
#define OC0 13         // first chunk covering t >= LL-PL (416/32)

// workspace layout (bytes).
// pre-gemm:  emb @0 (4MB), WinT @4M (2MB)    [both dead after k_gemm]
// post-gemm: BC @0 (512KB), yfin @1M (3MB), hin @4M (1.5MB), sumdt @5.5M (0.5MB)
#define EMB_OFF   0u
#define BC_OFF    0u
#define YFIN_OFF  (1u<<20)
#define WINT_OFF  (4u<<20)
#define HIN_OFF   (4u<<20)
#define SUMDT_OFF ((5u<<20) + (1u<<19))
#define WCOMB_OFF (6u<<20)
#define STATS_OFF (7u<<20)
#define XZ_OFF    (8u<<20)           // bf16 4096*2048  (16 MB)
#define XS_OFF    (24u<<20)          // f32  4096*1024  (16 MB)
#define DT_OFF    (40u<<20)          // f32  4096*1024  (16 MB)
#define HLOC_OFF  (56u<<20)          // bf16 8*16*16*1024 (4 MB)

static __device__ __forceinline__ float softplusf(float x) {
    return (x > 20.f) ? x : log1pf(__expf(x));
}
static __device__ __forceinline__ float siluf(float x) {
    return x / (1.f + __expf(-x));
}

// ---------------- per-(b,c) mean / std over L ----------------
__global__ void k_stats(const float* __restrict__ x, float* __restrict__ meanW,
                        float* __restrict__ stdW) {
    int bc = blockIdx.x; int b = bc / CIN, c = bc % CIN;
    const float* p = x + (size_t)b * LL * CIN + c;
    float s = 0.f, ss = 0.f;
    for (int t = threadIdx.x; t < LL; t += 256) {
        float v = p[(size_t)t * CIN];
        s += v; ss += v * v;
    }
    __shared__ float r1[256], r2[256];
    r1[threadIdx.x] = s; r2[threadIdx.x] = ss;
    __syncthreads();
    for (int off = 128; off > 0; off >>= 1) {
        if (threadIdx.x < off) {
            r1[threadIdx.x] += r1[threadIdx.x + off];
            r2[threadIdx.x] += r2[threadIdx.x + off];
        }
        __syncthreads();
    }
    if (threadIdx.x == 0) {
        float m = r1[0] / LL;
        float var = r2[0] / LL - m * m;
        meanW[bc] = m;
        stdW[bc]  = sqrtf(var + 1e-5f);
    }
}

// ---------------- embedding: xn @ W_emb + b_emb -> bf16 ----------------
__global__ void k_emb(const float* __restrict__ x, const float* __restrict__ W,
                      const float* __restrict__ bias, const float* __restrict__ meanW,
                      const float* __restrict__ stdW, bf16_t* __restrict__ emb) {
    int row0 = blockIdx.x * 4;
    int b = row0 >> 9;
    __shared__ float xn[4][CIN];
    int tid = threadIdx.x;
    if (tid < 4 * CIN) {
        int r = tid / CIN, c = tid % CIN;
        xn[r][c] = (x[(size_t)(row0 + r) * CIN + c] - meanW[b * CIN + c]) / stdW[b * CIN + c];
    }
    __syncthreads();
    int j0 = tid, j1 = tid + 256;
    float acc[4][2];
    float b0 = bias[j0], b1 = bias[j1];
    for (int r = 0; r < 4; ++r) { acc[r][0] = b0; acc[r][1] = b1; }
    for (int c = 0; c < CIN; ++c) {
        float w0 = W[c * DM + j0], w1 = W[c * DM + j1];
        for (int r = 0; r < 4; ++r) {
            acc[r][0] += xn[r][c] * w0;
            acc[r][1] += xn[r][c] * w1;
        }
    }
    for (int r = 0; r < 4; ++r) {
        emb[(size_t)(row0 + r) * DM + j0] = (bf16_t)acc[r][0];
        emb[(size_t)(row0 + r) * DM + j1] = (bf16_t)acc[r][1];
    }
}

// ---------------- W_in (512,2048) f32 -> W_in^T (2048,512) bf16 ----------------
__global__ void k_wint(const float* __restrict__ Win, bf16_t* __restrict__ WinT) {
    __shared__ float tile[32][33];
    int k0 = blockIdx.x * 32, n0 = blockIdx.y * 32;
    int x = threadIdx.x, y = threadIdx.y;
    for (int i = 0; i < 4; ++i)
        tile[y + 8 * i][x] = Win[(size_t)(k0 + y + 8 * i) * (2 * DI) + n0 + x];
    __syncthreads();
    for (int i = 0; i < 4; ++i)
        WinT[(size_t)(n0 + y + 8 * i) * DM + k0 + x] = (bf16_t)tile[x][y + 8 * i];
}

// ---------------- Wcomb = W_op @ W_head  (1024x21) ----------------
__global__ void k_wcomb(const float* __restrict__ Wop, const float* __restrict__ Wh,
                        float* __restrict__ Wc) {
    int i = blockIdx.x;
    __shared__ float row[DM];
    __shared__ float part[8][32];
    int tid = threadIdx.x;
    row[tid] = Wop[(size_t)i * DM + tid];
    row[tid + 256] = Wop[(size_t)i * DM + tid + 256];
    __syncthreads();
    int c = tid & 31, seg = tid >> 5;
    float p = 0.f;
    if (c < CIN) {
        for (int kk = 0; kk < 64; ++kk) {
            int k = seg * 64 + kk;
            p += row[k] * Wh[k * CIN + c];
        }
    }
    part[seg][c] = p;
    __syncthreads();
    if (tid < CIN) {
        float s = 0.f;
        for (int g = 0; g < 8; ++g) s += part[g][tid];
        Wc[i * CIN + tid] = s;
    }
}

// ---------------- big GEMM: xz = emb(4096x512) @ W_in  via bf16 MFMA ----------------
__launch_bounds__(256, 2)
__global__ void k_gemm(const bf16_t* __restrict__ A, const bf16_t* __restrict__ Bt,
                       bf16_t* __restrict__ C) {
    __shared__ bf16_t As[128 * 40];
    __shared__ bf16_t Bs[128 * 40];
    int m0 = blockIdx.x * 128, n0 = blockIdx.y * 128;
    int tid = threadIdx.x;
    int lane = tid & 63, wv = tid >> 6;
    int wr = wv >> 1, wc = wv & 1;
    int lr = lane & 15, lk = lane >> 4;
    f32x4 acc[4][4];
    for (int i = 0; i < 4; ++i)
        for (int j = 0; j < 4; ++j)
            acc[i][j] = (f32x4){0.f, 0.f, 0.f, 0.f};
    int srow = tid >> 2, scb = tid & 3;
    for (int kt = 0; kt < 16; ++kt) {
        int k0 = kt * 32;
        uint4 va0 = *(const uint4*)(A + (size_t)(m0 + srow) * DM + k0 + scb * 8);
        uint4 va1 = *(const uint4*)(A + (size_t)(m0 + srow + 64) * DM + k0 + scb * 8);
        uint4 vb0 = *(const uint4*)(Bt + (size_t)(n0 + srow) * DM + k0 + scb * 8);
        uint4 vb1 = *(const uint4*)(Bt + (size_t)(n0 + srow + 64) * DM + k0 + scb * 8);
        __syncthreads();
        *(uint4*)&As[srow * 40 + scb * 8] = va0;
        *(uint4*)&As[(srow + 64) * 40 + scb * 8] = va1;
        *(uint4*)&Bs[srow * 40 + scb * 8] = vb0;
        *(uint4*)&Bs[(srow + 64) * 40 + scb * 8] = vb1;
        __syncthreads();
        bf16x8 af[4], bfr[4];
        for (int i = 0; i < 4; ++i)
            af[i] = *(const bf16x8*)&As[(wr * 64 + i * 16 + lr) * 40 + lk * 8];
        for (int j = 0; j < 4; ++j)
            bfr[j] = *(const bf16x8*)&Bs[(wc * 64 + j * 16 + lr) * 40 + lk * 8];
        for (int i = 0; i < 4; ++i)
            for (int j = 0; j < 4; ++j)
                acc[i][j] = __builtin_amdgcn_mfma_f32_16x16x32_bf16(af[i], bfr[j], acc[i][j], 0, 0, 0);
    }
    for (int i = 0; i < 4; ++i)
        for (int j = 0; j < 4; ++j) {
            int col = n0 + wc * 64 + j * 16 + lr;
            int rbase = m0 + wr * 64 + i * 16 + lk * 4;
            for (int e = 0; e < 4; ++e)
                C[(size_t)(rbase + e) * (2 * DI) + col] = (bf16_t)acc[i][j][e];
        }
}

// ---------------- causal depthwise conv(k=4) + silu ----------------
__global__ void k_conv(const bf16_t* __restrict__ xz, const float* __restrict__ cw,
                       const float* __restrict__ cb, float* __restrict__ xs_act) {
    int g = blockIdx.x * 256 + threadIdx.x;
    int d = g & (DI - 1);
    int bt = g >> 10;
    int t = bt & (LL - 1);
    const bf16_t* p = xz + (size_t)bt * (2 * DI) + d;
    float4 w = *(const float4*)(cw + d * 4);
    float acc = cb[d];
    float x0 = (t >= 3) ? (float)p[-3 * 2048] : 0.f;
    float x1 = (t >= 2) ? (float)p[-2 * 2048] : 0.f;
    float x2 = (t >= 1) ? (float)p[-1 * 2048] : 0.f;
    float x3 = (float)p[0];
    acc += w.x * x0 + w.y * x1 + w.z * x2 + w.w * x3;
    xs_act[g] = siluf(acc);
}

// ---------------- dbc = xs@W_xp ; dt = softplus(dbc[:, :32]@W_dt + b_dt) ; B,C out ----
__global__ void k_dbcdt(const float* __restrict__ xs, const float* __restrict__ Wxp,
                        const float* __restrict__ Wdt, const float* __restrict__ bdt,
                        float* __restrict__ BC, float* __restrict__ dtO) {
    int bt0 = blockIdx.x * 4;
    __shared__ float xsL[4][DI];
    __shared__ float part[4][4][64];
    __shared__ float dbcL[4][64];
    int tid = threadIdx.x;
    for (int r = 0; r < 4; ++r)
        for (int i = tid; i < DI; i += 256)
            xsL[r][i] = xs[(size_t)(bt0 + r) * DI + i];
    __syncthreads();
    int j = tid & 63, cseg = tid >> 6;
    float p0 = 0, p1 = 0, p2 = 0, p3 = 0;
    for (int kk = 0; kk < 256; ++kk) {
        int k = cseg * 256 + kk;
        float w = Wxp[(size_t)k * 64 + j];
        p0 += xsL[0][k] * w; p1 += xsL[1][k] * w;
        p2 += xsL[2][k] * w; p3 += xsL[3][k] * w;
    }
    part[cseg][0][j] = p0; part[cseg][1][j] = p1;
    part[cseg][2][j] = p2; part[cseg][3][j] = p3;
    __syncthreads();
    {
        int jj = tid & 63, r = tid >> 6;
        float v = part[0][r][jj] + part[1][r][jj] + part[2][r][jj] + part[3][r][jj];
        dbcL[r][jj] = v;
        if (jj >= 32) BC[(size_t)(bt0 + r) * 32 + (jj - 32)] = v;
    }
    __syncthreads();
    for (int jo = tid; jo < DI; jo += 256) {
        float bb = bdt[jo];
        float a0 = bb, a1 = bb, a2 = bb, a3 = bb;
        for (int rk = 0; rk < RK; ++rk) {
            float w = Wdt[(size_t)rk * DI + jo];
            a0 += dbcL[0][rk] * w; a1 += dbcL[1][rk] * w;
            a2 += dbcL[2][rk] * w; a3 += dbcL[3][rk] * w;
        }
        dtO[(size_t)(bt0 + 0) * DI + jo] = softplusf(a0);
        dtO[(size_t)(bt0 + 1) * DI + jo] = softplusf(a1);
        dtO[(size_t)(bt0 + 2) * DI + jo] = softplusf(a2);
        dtO[(size_t)(bt0 + 3) * DI + jo] = softplusf(a3);
    }
}

// ---------------- scan phase 1: per-chunk local scan (h_in = 0) ----------------
// thread = (b, chunk, d); h[16] in registers; coalesced over d.
__global__ void k_scan1(const float* __restrict__ dt, const float* __restrict__ xs,
                        const float* __restrict__ BC, const float* __restrict__ Alog,
                        bf16_t* __restrict__ hloc, float* __restrict__ sumdt) {
    int idx = blockIdx.x * 256 + threadIdx.x;   // 8*16*1024
    int d = idx & (DI - 1);
    int rest = idx >> 10;
    int c = rest & (NCH - 1);
    int b = rest >> 4;
    float A[DS], h[DS];
    #pragma unroll
    for (int s = 0; s < DS; ++s) {
        A[s] = -__expf(Alog[d * DS + s]);
        h[s] = 0.f;
    }
    float sd = 0.f;
    int t0 = c * TC;
    const float* dtp = dt + ((size_t)b * LL + t0) * DI + d;
    const float* xsp = xs + ((size_t)b * LL + t0) * DI + d;
    const float* bcp = BC + ((size_t)(b * LL + t0)) * 32;
    #pragma unroll 4
    for (int tt = 0; tt < TC; ++tt) {
        float dtv = dtp[(size_t)tt * DI];
        float xv  = xsp[(size_t)tt * DI];
        float4 B0 = *(const float4*)(bcp + tt * 32 + 0);
        float4 B1 = *(const float4*)(bcp + tt * 32 + 4);
        float4 B2 = *(const float4*)(bcp + tt * 32 + 8);
        float4 B3 = *(const float4*)(bcp + tt * 32 + 12);
        float Bv[DS] = {B0.x, B0.y, B0.z, B0.w, B1.x, B1.y, B1.z, B1.w,
                        B2.x, B2.y, B2.z, B2.w, B3.x, B3.y, B3.z, B3.w};
        sd += dtv;
        float u = dtv * xv;
        #pragma unroll
        for (int s = 0; s < DS; ++s)
            h[s] = h[s] * __expf(dtv * A[s]) + u * Bv[s];
    }
    size_t hbase = (((size_t)b * NCH + c) * DS) * DI + d;
    #pragma unroll
    for (int s = 0; s < DS; ++s) hloc[hbase + (size_t)s * DI] = (bf16_t)h[s];
    sumdt[((size_t)b * NCH + c) * DI + d] = sd;
}

// ---------------- scan phase 2: combine chunk summaries; emit h_in for output chunks
// thread = (b, s, d)
__global__ void k_scan2(const bf16_t* __restrict__ hloc, const float* __restrict__ sumdt,
                        const float* __restrict__ Alog, float* __restrict__ hin) {
    int idx = blockIdx.x * 256 + threadIdx.x;   // 8*16*1024
    int d = idx & (DI - 1);
    int rest = idx >> 10;
    int s = rest & (DS - 1);
    int b = rest >> 4;
    float A = -__expf(Alog[d * DS + s]);
    float h = 0.f;
    #pragma unroll
    for (int c = 0; c < NCH; ++c) {
        if (c >= OC0)
            hin[(((size_t)b * 3 + (c - OC0)) * DS + s) * DI + d] = h;
        float da = __expf(A * sumdt[((size_t)b * NCH + c) * DI + d]);
        h = da * h + (float)hloc[(((size_t)b * NCH + c) * DS + s) * DI + d];
    }
}

// ---------------- scan phase 3: re-scan output chunks; fuse C-dot, D-skip, silu(z) gate
// thread = (b, oc, d)
__global__ void k_scan3(const float* __restrict__ dt, const float* __restrict__ xs,
                        const float* __restrict__ BC, const bf16_t* __restrict__ xz,
                        const float* __restrict__ Alog, const float* __restrict__ Dp,
                        const float* __restrict__ hin, float* __restrict__ yfin) {
    int idx = blockIdx.x * 256 + threadIdx.x;   // 8*3*1024
    int d = idx & (DI - 1);
    int rest = idx >> 10;
    int oc = rest % 3;
    int b = rest / 3;
    int c = OC0 + oc;
    int t0 = c * TC;
    float A[DS], h[DS];
    #pragma unroll
    for (int s = 0; s < DS; ++s) {
        A[s] = -__expf(Alog[d * DS + s]);
        h[s] = hin[(((size_t)b * 3 + oc) * DS + s) * DI + d];
    }
    float Dd = Dp[d];
    const float* dtp = dt + ((size_t)b * LL + t0) * DI + d;
    const float* xsp = xs + ((size_t)b * LL + t0) * DI + d;
    const float* bcp = BC + ((size_t)(b * LL + t0)) * 32;
    const bf16_t* zp = xz + ((size_t)b * LL + t0) * (2 * DI) + DI + d;
    float* yp = yfin + ((size_t)b * PL + (size_t)oc * TC) * DI + d;
    #pragma unroll 2
    for (int tt = 0; tt < TC; ++tt) {
        float dtv = dtp[(size_t)tt * DI];
        float xv  = xsp[(size_t)tt * DI];
        float4 B0 = *(const float4*)(bcp + tt * 32 + 0);
        float4 B1 = *(const float4*)(bcp + tt * 32 + 4);
        float4 B2 = *(const float4*)(bcp + tt * 32 + 8);
        float4 B3 = *(const float4*)(bcp + tt * 32 + 12);
        float4 C0 = *(const float4*)(bcp + tt * 32 + 16);
        float4 C1 = *(const float4*)(bcp + tt * 32 + 20);
        float4 C2 = *(const float4*)(bcp + tt * 32 + 24);
        float4 C3 = *(const float4*)(bcp + tt * 32 + 28);
        float Bv[DS] = {B0.x, B0.y, B0.z, B0.w, B1.x, B1.y, B1.z, B1.w,
                        B2.x, B2.y, B2.z, B2.w, B3.x, B3.y, B3.z, B3.w};
        float Cv[DS] = {C0.x, C0.y, C0.z, C0.w, C1.x, C1.y, C1.z, C1.w,
                        C2.x, C2.y, C2.z, C2.w, C3.x, C3.y, C3.z, C3.w};
        float u = dtv * xv;
        float y = 0.f;
        #pragma unroll
        for (int s = 0; s < DS; ++s) {
            h[s] = h[s] * __expf(dtv * A[s]) + u * Bv[s];
            y += h[s] * Cv[s];
        }
        float zv = (float)zp[(size_t)tt * (2 * DI)];
        yp[(size_t)tt * DI] = (y + xv * Dd) * siluf(zv);
    }
}

// ---------------- out = (yfin @ Wcomb + b_head) * std + mean ----------------
__global__ void k_head(const float* __restrict__ yfin, const float* __restrict__ Wc,
                       const float* __restrict__ bh, const float* __restrict__ meanW,
                       const float* __restrict__ stdW, float* __restrict__ out) {
    int row = blockIdx.x;              // 768 = 8*96
    int b = row / PL;
    __shared__ float yL[DI];
    __shared__ float part[8][32];
    int tid = threadIdx.x;
    *(float4*)&yL[tid * 4] = *(const float4*)&yfin[(size_t)row * DI + tid * 4];
    __syncthreads();
    int c = tid & 31, seg = tid >> 5;
    float acc = 0.f;
    if (c < CIN) {
        for (int kk = 0; kk < 128; ++kk) {
            int k = seg * 128 + kk;
            acc += yL[k] * Wc[k * CIN + c];
        }
    }
    part[seg][c] = acc;
    __syncthreads();
    if (tid < CIN) {
        float sum = bh[tid];
        for (int g = 0; g < 8; ++g) sum += part[g][tid];
        out[(size_t)row * CIN + tid] = sum * stdW[b * CIN + tid] + meanW[b * CIN + tid];
    }
}

extern "C" void kernel_launch(void* const* d_in, const int* in_sizes, int n_in,
                              void* d_out, int out_size, void* d_ws, size_t ws_size,
                              hipStream_t stream) {
    const float* x_enc  = (const float*)d_in[0];
    const float* W_emb  = (const float*)d_in[4];
    const float* b_emb  = (const float*)d_in[5];
    const float* W_in   = (const float*)d_in[6];
    const float* conv_w = (const float*)d_in[7];
    const float* conv_b = (const float*)d_in[8];
    const float* W_xp   = (const float*)d_in[9];
    const float* W_dt   = (const float*)d_in[10];
    const float* b_dt   = (const float*)d_in[11];
    const float* A_log  = (const float*)d_in[12];
    const float* Dp     = (const float*)d_in[13];
    const float* W_op   = (const float*)d_in[14];
    const float* W_head = (const float*)d_in[15];
    const float* b_head = (const float*)d_in[16];

    char* ws = (char*)d_ws;
    bf16_t* emb   = (bf16_t*)(ws + EMB_OFF);
    bf16_t* WinT  = (bf16_t*)(ws + WINT_OFF);
    float*  Wcomb = (float*)(ws + WCOMB_OFF);
    float*  meanW = (float*)(ws + STATS_OFF);
    float*  stdW  = meanW + 256;
    bf16_t* xz    = (bf16_t*)(ws + XZ_OFF);
    float*  xsact = (float*)(ws + XS_OFF);
    float*  dtb   = (float*)(ws + DT_OFF);
    float*  BCb   = (float*)(ws + BC_OFF);
    float*  yfin  = (float*)(ws + YFIN_OFF);
    bf16_t* hloc  = (bf16_t*)(ws + HLOC_OFF);
    float*  sumdt = (float*)(ws + SUMDT_OFF);
    float*  hin   = (float*)(ws + HIN_OFF);
    float*  outp  = (float*)d_out;

    k_stats<<<BB * CIN, 256, 0, stream>>>(x_enc, meanW, stdW);
    k_emb<<<NROW / 4, 256, 0, stream>>>(x_enc, W_emb, b_emb, meanW, stdW, emb);
    k_wint<<<dim3(DM / 32, (2 * DI) / 32), dim3(32, 8), 0, stream>>>(W_in, WinT);
    k_wcomb<<<DI, 256, 0, stream>>>(W_op, W_head, Wcomb);
    k_gemm<<<dim3(NROW / 128, (2 * DI) / 128), 256, 0, stream>>>(emb, WinT, xz);
    k_conv<<<(NROW * DI) / 256, 256, 0, stream>>>(xz, conv_w, conv_b, xsact);
    k_dbcdt<<<NROW / 4, 256, 0, stream>>>(xsact, W_xp, W_dt, b_dt, BCb, dtb);
    k_scan1<<<(BB * NCH * DI) / 256, 256, 0, stream>>>(dtb, xsact, BCb, A_log, hloc, sumdt);
    k_scan2<<<(BB * DS * DI) / 256, 256, 0, stream>>>(hloc, sumdt, A_log, hin);
    k_scan3<<<(BB * 3 * DI) / 256, 256, 0, stream>>>(dtb, xsact, BCb, xz, A_log, Dp, hin, yfin);
    k_head<<<BB * PL, 256, 0, stream>>>(yfin, Wcomb, b_head, meanW, stdW, outp);
}

// Round 3
// 162.771 us; speedup vs baseline: 2.2212x; 1.0798x over previous
//
#include <hip/hip_runtime.h>
#include <hip/hip_bf16.h>
#include <math.h>

typedef __bf16 bf16_t;
typedef __bf16 bf16x8 __attribute__((ext_vector_type(8)));
typedef float f32x4 __attribute__((ext_vector_type(4)));

#define BB 8
#define LL 512
#define CIN 21
#define DM 512
#define DI 1024
#define DS 16
#define RK 32
#define PL 96
#define NROW (BB*LL)   // 4096
#define NCH 16         // scan chunks
#define TC 32          // steps per chunk (LL/NCH)
#define OC0 13         // first chunk covering t >= LL-PL (416/32)

// workspace layout (bytes).
// pre-gemm:  emb @0 (4MB), WinT @4M (2MB)    [both dead after k_gemm]
// post-gemm: BC @0 (512KB), dbcD @512K (512KB), yfin @1M (3MB), hin @4M, sumdt @5.5M
#define EMB_OFF   0u
#define BC_OFF    0u
#define DBC_OFF   (1u<<19)
#define YFIN_OFF  (1u<<20)
#define WINT_OFF  (4u<<20)
#define HIN_OFF   (4u<<20)
#define SUMDT_OFF ((5u<<20) + (1u<<19))
#define WCOMB_OFF (6u<<20)
#define WXPT_OFF  ((6u<<20) + (1u<<19))
#define STATS_OFF (7u<<20)
#define XZ_OFF    (8u<<20)           // bf16 4096*2048  (16 MB)
#define XS_OFF    (24u<<20)          // f32  4096*1024  (16 MB)
#define DT_OFF    (40u<<20)          // f32  4096*1024  (16 MB)
#define HLOC_OFF  (56u<<20)          // bf16 8*16*16*1024 (4 MB)

static __device__ __forceinline__ float softplusf(float x) {
    return (x > 20.f) ? x : log1pf(__expf(x));
}
static __device__ __forceinline__ float siluf(float x) {
    return x / (1.f + __expf(-x));
}

// ---------------- per-(b,c) mean / std over L ----------------
__global__ void k_stats(const float* __restrict__ x, float* __restrict__ meanW,
                        float* __restrict__ stdW) {
    int bc = blockIdx.x; int b = bc / CIN, c = bc % CIN;
    const float* p = x + (size_t)b * LL * CIN + c;
    float s = 0.f, ss = 0.f;
    for (int t = threadIdx.x; t < LL; t += 256) {
        float v = p[(size_t)t * CIN];
        s += v; ss += v * v;
    }
    __shared__ float r1[256], r2[256];
    r1[threadIdx.x] = s; r2[threadIdx.x] = ss;
    __syncthreads();
    for (int off = 128; off > 0; off >>= 1) {
        if (threadIdx.x < off) {
            r1[threadIdx.x] += r1[threadIdx.x + off];
            r2[threadIdx.x] += r2[threadIdx.x + off];
        }
        __syncthreads();
    }
    if (threadIdx.x == 0) {
        float m = r1[0] / LL;
        float var = r2[0] / LL - m * m;
        meanW[bc] = m;
        stdW[bc]  = sqrtf(var + 1e-5f);
    }
}

// ---------------- embedding: xn @ W_emb + b_emb -> bf16 ----------------
__global__ void k_emb(const float* __restrict__ x, const float* __restrict__ W,
                      const float* __restrict__ bias, const float* __restrict__ meanW,
                      const float* __restrict__ stdW, bf16_t* __restrict__ emb) {
    int row0 = blockIdx.x * 4;
    int b = row0 >> 9;
    __shared__ float xn[4][CIN];
    int tid = threadIdx.x;
    if (tid < 4 * CIN) {
        int r = tid / CIN, c = tid % CIN;
        xn[r][c] = (x[(size_t)(row0 + r) * CIN + c] - meanW[b * CIN + c]) / stdW[b * CIN + c];
    }
    __syncthreads();
    int j0 = tid, j1 = tid + 256;
    float acc[4][2];
    float b0 = bias[j0], b1 = bias[j1];
    for (int r = 0; r < 4; ++r) { acc[r][0] = b0; acc[r][1] = b1; }
    for (int c = 0; c < CIN; ++c) {
        float w0 = W[c * DM + j0], w1 = W[c * DM + j1];
        for (int r = 0; r < 4; ++r) {
            acc[r][0] += xn[r][c] * w0;
            acc[r][1] += xn[r][c] * w1;
        }
    }
    for (int r = 0; r < 4; ++r) {
        emb[(size_t)(row0 + r) * DM + j0] = (bf16_t)acc[r][0];
        emb[(size_t)(row0 + r) * DM + j1] = (bf16_t)acc[r][1];
    }
}

// ---------------- generic f32 (R,C) -> bf16 transpose (C,R) ----------------
__global__ void k_t32(const float* __restrict__ in, bf16_t* __restrict__ out,
                      int R, int C) {
    __shared__ float tile[32][33];
    int r0 = blockIdx.x * 32, c0 = blockIdx.y * 32;
    int x = threadIdx.x, y = threadIdx.y;
    for (int i = 0; i < 4; ++i)
        tile[y + 8 * i][x] = in[(size_t)(r0 + y + 8 * i) * C + c0 + x];
    __syncthreads();
    for (int i = 0; i < 4; ++i)
        out[(size_t)(c0 + y + 8 * i) * R + r0 + x] = (bf16_t)tile[x][y + 8 * i];
}

// ---------------- Wcomb = W_op @ W_head  (1024x21) ----------------
__global__ void k_wcomb(const float* __restrict__ Wop, const float* __restrict__ Wh,
                        float* __restrict__ Wc) {
    int i = blockIdx.x;
    __shared__ float row[DM];
    __shared__ float part[8][32];
    int tid = threadIdx.x;
    row[tid] = Wop[(size_t)i * DM + tid];
    row[tid + 256] = Wop[(size_t)i * DM + tid + 256];
    __syncthreads();
    int c = tid & 31, seg = tid >> 5;
    float p = 0.f;
    if (c < CIN) {
        for (int kk = 0; kk < 64; ++kk) {
            int k = seg * 64 + kk;
            p += row[k] * Wh[k * CIN + c];
        }
    }
    part[seg][c] = p;
    __syncthreads();
    if (tid < CIN) {
        float s = 0.f;
        for (int g = 0; g < 8; ++g) s += part[g][tid];
        Wc[i * CIN + tid] = s;
    }
}

// ---------------- big GEMM: xz = emb(4096x512) @ W_in  via bf16 MFMA ----------------
__launch_bounds__(256, 2)
__global__ void k_gemm(const bf16_t* __restrict__ A, const bf16_t* __restrict__ Bt,
                       bf16_t* __restrict__ C) {
    __shared__ bf16_t As[128 * 40];
    __shared__ bf16_t Bs[128 * 40];
    int m0 = blockIdx.x * 128, n0 = blockIdx.y * 128;
    int tid = threadIdx.x;
    int lane = tid & 63, wv = tid >> 6;
    int wr = wv >> 1, wc = wv & 1;
    int lr = lane & 15, lk = lane >> 4;
    f32x4 acc[4][4];
    for (int i = 0; i < 4; ++i)
        for (int j = 0; j < 4; ++j)
            acc[i][j] = (f32x4){0.f, 0.f, 0.f, 0.f};
    int srow = tid >> 2, scb = tid & 3;
    for (int kt = 0; kt < 16; ++kt) {
        int k0 = kt * 32;
        uint4 va0 = *(const uint4*)(A + (size_t)(m0 + srow) * DM + k0 + scb * 8);
        uint4 va1 = *(const uint4*)(A + (size_t)(m0 + srow + 64) * DM + k0 + scb * 8);
        uint4 vb0 = *(const uint4*)(Bt + (size_t)(n0 + srow) * DM + k0 + scb * 8);
        uint4 vb1 = *(const uint4*)(Bt + (size_t)(n0 + srow + 64) * DM + k0 + scb * 8);
        __syncthreads();
        *(uint4*)&As[srow * 40 + scb * 8] = va0;
        *(uint4*)&As[(srow + 64) * 40 + scb * 8] = va1;
        *(uint4*)&Bs[srow * 40 + scb * 8] = vb0;
        *(uint4*)&Bs[(srow + 64) * 40 + scb * 8] = vb1;
        __syncthreads();
        bf16x8 af[4], bfr[4];
        for (int i = 0; i < 4; ++i)
            af[i] = *(const bf16x8*)&As[(wr * 64 + i * 16 + lr) * 40 + lk * 8];
        for (int j = 0; j < 4; ++j)
            bfr[j] = *(const bf16x8*)&Bs[(wc * 64 + j * 16 + lr) * 40 + lk * 8];
        for (int i = 0; i < 4; ++i)
            for (int j = 0; j < 4; ++j)
                acc[i][j] = __builtin_amdgcn_mfma_f32_16x16x32_bf16(af[i], bfr[j], acc[i][j], 0, 0, 0);
    }
    for (int i = 0; i < 4; ++i)
        for (int j = 0; j < 4; ++j) {
            int col = n0 + wc * 64 + j * 16 + lr;
            int rbase = m0 + wr * 64 + i * 16 + lk * 4;
            for (int e = 0; e < 4; ++e)
                C[(size_t)(rbase + e) * (2 * DI) + col] = (bf16_t)acc[i][j][e];
        }
}

// ---------------- causal depthwise conv(k=4) + silu ----------------
__global__ void k_conv(const bf16_t* __restrict__ xz, const float* __restrict__ cw,
                       const float* __restrict__ cb, float* __restrict__ xs_act) {
    int g = blockIdx.x * 256 + threadIdx.x;
    int d = g & (DI - 1);
    int bt = g >> 10;
    int t = bt & (LL - 1);
    const bf16_t* p = xz + (size_t)bt * (2 * DI) + d;
    float4 w = *(const float4*)(cw + d * 4);
    float acc = cb[d];
    float x0 = (t >= 3) ? (float)p[-3 * 2048] : 0.f;
    float x1 = (t >= 2) ? (float)p[-2 * 2048] : 0.f;
    float x2 = (t >= 1) ? (float)p[-1 * 2048] : 0.f;
    float x3 = (float)p[0];
    acc += w.x * x0 + w.y * x1 + w.z * x2 + w.w * x3;
    xs_act[g] = siluf(acc);
}

// ---------------- dbc GEMM: xs(4096x1024) @ Wxp(1024x64) via MFMA ----------------
// WxpT: (64,1024) bf16.  cols 0..31 -> dbcD, cols 32..63 -> BC
__launch_bounds__(256, 2)
__global__ void k_dbc(const float* __restrict__ xs, const bf16_t* __restrict__ WxpT,
                      float* __restrict__ dbcD, float* __restrict__ BC) {
    __shared__ bf16_t As[64 * 136];   // 64 rows x (128 data + 8 pad)
    __shared__ bf16_t Bs[64 * 136];
    int m0 = blockIdx.x * 64;
    int tid = threadIdx.x;
    int lane = tid & 63, wv = tid >> 6;
    int lr = lane & 15, lk = lane >> 4;
    f32x4 acc[4];
    for (int j = 0; j < 4; ++j) acc[j] = (f32x4){0.f, 0.f, 0.f, 0.f};
    int srow = tid >> 2, scq = (tid & 3) * 32;
    for (int kt = 0; kt < 8; ++kt) {
        int k0 = kt * 128;
        const float* ap = xs + (size_t)(m0 + srow) * DI + k0 + scq;
        float4 a4[8];
        #pragma unroll
        for (int i = 0; i < 8; ++i) a4[i] = *(const float4*)(ap + i * 4);
        const bf16_t* bp = WxpT + (size_t)srow * DI + k0 + scq;
        uint4 b4[4];
        #pragma unroll
        for (int i = 0; i < 4; ++i) b4[i] = *(const uint4*)(bp + i * 8);
        __syncthreads();
        bf16_t tmp[32];
        #pragma unroll
        for (int i = 0; i < 8; ++i) {
            tmp[i * 4 + 0] = (bf16_t)a4[i].x;
            tmp[i * 4 + 1] = (bf16_t)a4[i].y;
            tmp[i * 4 + 2] = (bf16_t)a4[i].z;
            tmp[i * 4 + 3] = (bf16_t)a4[i].w;
        }
        bf16_t* aw = &As[srow * 136 + scq];
        #pragma unroll
        for (int i = 0; i < 4; ++i) *(uint4*)(aw + i * 8) = *(const uint4*)(tmp + i * 8);
        bf16_t* bw = &Bs[srow * 136 + scq];
        #pragma unroll
        for (int i = 0; i < 4; ++i) *(uint4*)(bw + i * 8) = b4[i];
        __syncthreads();
        #pragma unroll
        for (int kk = 0; kk < 4; ++kk) {
            bf16x8 af = *(const bf16x8*)&As[(wv * 16 + lr) * 136 + kk * 32 + lk * 8];
            #pragma unroll
            for (int j = 0; j < 4; ++j) {
                bf16x8 bfr = *(const bf16x8*)&Bs[(j * 16 + lr) * 136 + kk * 32 + lk * 8];
                acc[j] = __builtin_amdgcn_mfma_f32_16x16x32_bf16(af, bfr, acc[j], 0, 0, 0);
            }
        }
    }
    #pragma unroll
    for (int j = 0; j < 4; ++j) {
        int col = j * 16 + lr;
        #pragma unroll
        for (int e = 0; e < 4; ++e) {
            int row = m0 + wv * 16 + lk * 4 + e;
            if (j < 2) dbcD[(size_t)row * 32 + col] = acc[j][e];
            else       BC[(size_t)row * 32 + (col - 32)] = acc[j][e];
        }
    }
}

// ---------------- dt = softplus(dbcD(4096x32) @ Wdt(32x1024) + b_dt) ----------------
// dbc rows read via wave-uniform (scalar) loads; Wdt columns in VGPRs.
__global__ void k_dt(const float* __restrict__ dbcD, const float* __restrict__ Wdt,
                     const float* __restrict__ bdt, float* __restrict__ dtO) {
    int r0 = (blockIdx.x >> 1) * 32;
    int c0 = (blockIdx.x & 1) * 512;
    int tid = threadIdx.x;
    int d0 = c0 + tid, d1 = c0 + tid + 256;
    float w0[RK], w1[RK];
    #pragma unroll
    for (int k = 0; k < RK; ++k) {
        w0[k] = Wdt[(size_t)k * DI + d0];
        w1[k] = Wdt[(size_t)k * DI + d1];
    }
    float b0 = bdt[d0], b1 = bdt[d1];
    for (int r = 0; r < 32; ++r) {
        const float* row = dbcD + (size_t)(r0 + r) * 32;
        float a0 = b0, a1 = b1;
        #pragma unroll
        for (int k = 0; k < RK; ++k) {
            float s = row[k];
            a0 += s * w0[k];
            a1 += s * w1[k];
        }
        dtO[(size_t)(r0 + r) * DI + d0] = softplusf(a0);
        dtO[(size_t)(r0 + r) * DI + d1] = softplusf(a1);
    }
}

// ---------------- scan phase 1: per-chunk local scan (h_in = 0) ----------------
__global__ void k_scan1(const float* __restrict__ dt, const float* __restrict__ xs,
                        const float* __restrict__ BC, const float* __restrict__ Alog,
                        bf16_t* __restrict__ hloc, float* __restrict__ sumdt) {
    int idx = blockIdx.x * 256 + threadIdx.x;   // 8*16*1024
    int d = idx & (DI - 1);
    int rest = idx >> 10;
    int c = rest & (NCH - 1);
    int b = rest >> 4;
    float A[DS], h[DS];
    #pragma unroll
    for (int s = 0; s < DS; ++s) {
        A[s] = -__expf(Alog[d * DS + s]);
        h[s] = 0.f;
    }
    float sd = 0.f;
    int t0 = c * TC;
    const float* dtp = dt + ((size_t)b * LL + t0) * DI + d;
    const float* xsp = xs + ((size_t)b * LL + t0) * DI + d;
    const float* bcp = BC + ((size_t)(b * LL + t0)) * 32;
    #pragma unroll 4
    for (int tt = 0; tt < TC; ++tt) {
        float dtv = dtp[(size_t)tt * DI];
        float xv  = xsp[(size_t)tt * DI];
        float4 B0 = *(const float4*)(bcp + tt * 32 + 0);
        float4 B1 = *(const float4*)(bcp + tt * 32 + 4);
        float4 B2 = *(const float4*)(bcp + tt * 32 + 8);
        float4 B3 = *(const float4*)(bcp + tt * 32 + 12);
        float Bv[DS] = {B0.x, B0.y, B0.z, B0.w, B1.x, B1.y, B1.z, B1.w,
                        B2.x, B2.y, B2.z, B2.w, B3.x, B3.y, B3.z, B3.w};
        sd += dtv;
        float u = dtv * xv;
        #pragma unroll
        for (int s = 0; s < DS; ++s)
            h[s] = h[s] * __expf(dtv * A[s]) + u * Bv[s];
    }
    size_t hbase = (((size_t)b * NCH + c) * DS) * DI + d;
    #pragma unroll
    for (int s = 0; s < DS; ++s) hloc[hbase + (size_t)s * DI] = (bf16_t)h[s];
    sumdt[((size_t)b * NCH + c) * DI + d] = sd;
}

// ---------------- scan phase 2: combine chunk summaries ----------------
__global__ void k_scan2(const bf16_t* __restrict__ hloc, const float* __restrict__ sumdt,
                        const float* __restrict__ Alog, float* __restrict__ hin) {
    int idx = blockIdx.x * 256 + threadIdx.x;   // 8*16*1024
    int d = idx & (DI - 1);
    int rest = idx >> 10;
    int s = rest & (DS - 1);
    int b = rest >> 4;
    float A = -__expf(Alog[d * DS + s]);
    float h = 0.f;
    #pragma unroll
    for (int c = 0; c < NCH; ++c) {
        if (c >= OC0)
            hin[(((size_t)b * 3 + (c - OC0)) * DS + s) * DI + d] = h;
        float da = __expf(A * sumdt[((size_t)b * NCH + c) * DI + d]);
        h = da * h + (float)hloc[(((size_t)b * NCH + c) * DS + s) * DI + d];
    }
}

// ---------------- scan phase 3: output chunks; fuse C-dot, D-skip, silu(z) ----------
__global__ void k_scan3(const float* __restrict__ dt, const float* __restrict__ xs,
                        const float* __restrict__ BC, const bf16_t* __restrict__ xz,
                        const float* __restrict__ Alog, const float* __restrict__ Dp,
                        const float* __restrict__ hin, float* __restrict__ yfin) {
    int idx = blockIdx.x * 256 + threadIdx.x;   // 8*3*1024
    int d = idx & (DI - 1);
    int rest = idx >> 10;
    int oc = rest % 3;
    int b = rest / 3;
    int c = OC0 + oc;
    int t0 = c * TC;
    float A[DS], h[DS];
    #pragma unroll
    for (int s = 0; s < DS; ++s) {
        A[s] = -__expf(Alog[d * DS + s]);
        h[s] = hin[(((size_t)b * 3 + oc) * DS + s) * DI + d];
    }
    float Dd = Dp[d];
    const float* dtp = dt + ((size_t)b * LL + t0) * DI + d;
    const float* xsp = xs + ((size_t)b * LL + t0) * DI + d;
    const float* bcp = BC + ((size_t)(b * LL + t0)) * 32;
    const bf16_t* zp = xz + ((size_t)b * LL + t0) * (2 * DI) + DI + d;
    float* yp = yfin + ((size_t)b * PL + (size_t)oc * TC) * DI + d;
    #pragma unroll 2
    for (int tt = 0; tt < TC; ++tt) {
        float dtv = dtp[(size_t)tt * DI];
        float xv  = xsp[(size_t)tt * DI];
        float4 B0 = *(const float4*)(bcp + tt * 32 + 0);
        float4 B1 = *(const float4*)(bcp + tt * 32 + 4);
        float4 B2 = *(const float4*)(bcp + tt * 32 + 8);
        float4 B3 = *(const float4*)(bcp + tt * 32 + 12);
        float4 C0 = *(const float4*)(bcp + tt * 32 + 16);
        float4 C1 = *(const float4*)(bcp + tt * 32 + 20);
        float4 C2 = *(const float4*)(bcp + tt * 32 + 24);
        float4 C3 = *(const float4*)(bcp + tt * 32 + 28);
        float Bv[DS] = {B0.x, B0.y, B0.z, B0.w, B1.x, B1.y, B1.z, B1.w,
                        B2.x, B2.y, B2.z, B2.w, B3.x, B3.y, B3.z, B3.w};
        float Cv[DS] = {C0.x, C0.y, C0.z, C0.w, C1.x, C1.y, C1.z, C1.w,
                        C2.x, C2.y, C2.z, C2.w, C3.x, C3.y, C3.z, C3.w};
        float u = dtv * xv;
        float y = 0.f;
        #pragma unroll
        for (int s = 0; s < DS; ++s) {
            h[s] = h[s] * __expf(dtv * A[s]) + u * Bv[s];
            y += h[s] * Cv[s];
        }
        float zv = (float)zp[(size_t)tt * (2 * DI)];
        yp[(size_t)tt * DI] = (y + xv * Dd) * siluf(zv);
    }
}

// ---------------- out = (yfin @ Wcomb + b_head) * std + mean ----------------
__global__ void k_head(const float* __restrict__ yfin, const float* __restrict__ Wc,
                       const float* __restrict__ bh, const float* __restrict__ meanW,
                       const float* __restrict__ stdW, float* __restrict__ out) {
    int row = blockIdx.x;              // 768 = 8*96
    int b = row / PL;
    __shared__ float yL[DI];
    __shared__ float part[8][32];
    int tid = threadIdx.x;
    *(float4*)&yL[tid * 4] = *(const float4*)&yfin[(size_t)row * DI + tid * 4];
    __syncthreads();
    int c = tid & 31, seg = tid >> 5;
    float acc = 0.f;
    if (c < CIN) {
        for (int kk = 0; kk < 128; ++kk) {
            int k = seg * 128 + kk;
            acc += yL[k] * Wc[k * CIN + c];
        }
    }
    part[seg][c] = acc;
    __syncthreads();
    if (tid < CIN) {
        float sum = bh[tid];
        for (int g = 0; g < 8; ++g) sum += part[g][tid];
        out[(size_t)row * CIN + tid] = sum * stdW[b * CIN + tid] + meanW[b * CIN + tid];
    }
}

extern "C" void kernel_launch(void* const* d_in, const int* in_sizes, int n_in,
                              void* d_out, int out_size, void* d_ws, size_t ws_size,
                              hipStream_t stream) {
    const float* x_enc  = (const float*)d_in[0];
    const float* W_emb  = (const float*)d_in[4];
    const float* b_emb  = (const float*)d_in[5];
    const float* W_in   = (const float*)d_in[6];
    const float* conv_w = (const float*)d_in[7];
    const float* conv_b = (const float*)d_in[8];
    const float* W_xp   = (const float*)d_in[9];
    const float* W_dt   = (const float*)d_in[10];
    const float* b_dt   = (const float*)d_in[11];
    const float* A_log  = (const float*)d_in[12];
    const float* Dp     = (const float*)d_in[13];
    const float* W_op   = (const float*)d_in[14];
    const float* W_head = (const float*)d_in[15];
    const float* b_head = (const float*)d_in[16];

    char* ws = (char*)d_ws;
    bf16_t* emb   = (bf16_t*)(ws + EMB_OFF);
    bf16_t* WinT  = (bf16_t*)(ws + WINT_OFF);
    bf16_t* WxpT  = (bf16_t*)(ws + WXPT_OFF);
    float*  Wcomb = (float*)(ws + WCOMB_OFF);
    float*  meanW = (float*)(ws + STATS_OFF);
    float*  stdW  = meanW + 256;
    bf16_t* xz    = (bf16_t*)(ws + XZ_OFF);
    float*  xsact = (float*)(ws + XS_OFF);
    float*  dtb   = (float*)(ws + DT_OFF);
    float*  BCb   = (float*)(ws + BC_OFF);
    float*  dbcD  = (float*)(ws + DBC_OFF);
    float*  yfin  = (float*)(ws + YFIN_OFF);
    bf16_t* hloc  = (bf16_t*)(ws + HLOC_OFF);
    float*  sumdt = (float*)(ws + SUMDT_OFF);
    float*  hin   = (float*)(ws + HIN_OFF);
    float*  outp  = (float*)d_out;

    k_stats<<<BB * CIN, 256, 0, stream>>>(x_enc, meanW, stdW);
    k_emb<<<NROW / 4, 256, 0, stream>>>(x_enc, W_emb, b_emb, meanW, stdW, emb);
    k_t32<<<dim3(DM / 32, (2 * DI) / 32), dim3(32, 8), 0, stream>>>(W_in, WinT, DM, 2 * DI);
    k_t32<<<dim3(DI / 32, 64 / 32), dim3(32, 8), 0, stream>>>(W_xp, WxpT, DI, 64);
    k_wcomb<<<DI, 256, 0, stream>>>(W_op, W_head, Wcomb);
    k_gemm<<<dim3(NROW / 128, (2 * DI) / 128), 256, 0, stream>>>(emb, WinT, xz);
    k_conv<<<(NROW * DI) / 256, 256, 0, stream>>>(xz, conv_w, conv_b, xsact);
    k_dbc<<<NROW / 64, 256, 0, stream>>>(xsact, WxpT, dbcD, BCb);
    k_dt<<<256, 256, 0, stream>>>(dbcD, W_dt, b_dt, dtb);
    k_scan1<<<(BB * NCH * DI) / 256, 256, 0, stream>>>(dtb, xsact, BCb, A_log, hloc, sumdt);
    k_scan2<<<(BB * DS * DI) / 256, 256, 0, stream>>>(hloc, sumdt, A_log, hin);
    k_scan3<<<(BB * 3 * DI) / 256, 256, 0, stream>>>(dtb, xsact, BCb, xz, A_log, Dp, hin, yfin);
    k_head<<<BB * PL, 256, 0, stream>>>(yfin, Wcomb, b_head, meanW, stdW, outp);
}